// Round 8
// baseline (545.224 us; speedup 1.0000x reference)
//
#include <hip/hip_runtime.h>

// Swin window attention, 4-kernel register-resident MFMA pipeline.
// B=4096, N=64, C=180, H=6, D=30 (pad 32), WNum=1024.
//
// Round-8 = round-7 structure + race fix in proj_kernel z-staging:
//   each (row, col-slot) of the LDS tile is written by EXACTLY ONE thread
//   (slot 22 = load 176..179 + zero 180..183, slot 23 = zero 184..191).
//   Round 7's cross-wave load/zero race read stale d_out on graph replays.
//
//   k1 prep_w  : weights -> bf16 fragment-friendly layouts + relb gather
//   k2 prep_x  : x -> PRE-FRAGMENTED bf16 xbf[b][ks][tt][lane] (16B/lane loads)
//   k3 swin_attn: 128-thr blocks (2 waves = 2 heads of one window), ZERO LDS,
//                ZERO barriers, <=128 regs -> 8 blocks/CU = 16 waves.
//                z (bf16 [64][192]) written into d_out's own window region.
//   k4 proj    : per-window 256-thr block: stage z->LDS, barrier, GEMM x wproj
//                + bias, overwrite region with final f32.
//
// Fragment-permutation trick (verified r2-r5): MFMA contracts A-slot(g,s) with
// B-slot(g,s); q/k fragments carry d(g,s)=16*(s>=4)+4g+(s&3) and P/V fragments
// carry j(g,s,k2)=32k2+16*(s>=4)+4g+(s&3) -- identical bijections on both
// operands, so no cross-lane traffic anywhere.

typedef __bf16 bf16;
typedef bf16 bf16x8 __attribute__((ext_vector_type(8)));
typedef float f32x4 __attribute__((ext_vector_type(4)));

#define MFMA(a, b, c) __builtin_amdgcn_mfma_f32_16x16x32_bf16(a, b, c, 0, 0, 0)

// ---------------- k1: weight prep ----------------
__global__ void prep_w(const float* __restrict__ wqkv,
                       const float* __restrict__ wproj,
                       const float* __restrict__ btab,
                       bf16* __restrict__ wqkvT,
                       bf16* __restrict__ wprojT,
                       float* __restrict__ relb)
{
    const int idx = blockIdx.x * 256 + threadIdx.x;
    if (idx < 110592) {                          // wqkvT [576][192], oc=h*96+sec*32+d
        const int oc = idx / 192, kk = idx - oc * 192;
        const int h = oc / 96, r = oc - h * 96;
        const int sec = r >> 5, d = r & 31;
        wqkvT[idx] = (bf16)((kk < 180 && d < 30) ? wqkv[kk * 540 + sec * 180 + h * 30 + d] : 0.f);
    } else if (idx < 147456) {                   // wprojT [192][192] n-major
        const int r = idx - 110592;
        const int n = r / 192, k = r - n * 192;
        wprojT[r] = (bf16)((n < 180 && k < 180) ? wproj[k * 180 + n] : 0.f);
    } else if (idx < 172032) {                   // relb [6][64][64]
        const int r = idx - 147456;
        const int h = r >> 12;
        const int ij = r & 4095;
        const int i = ij >> 6, j = ij & 63;
        const int rel = ((i >> 3) - (j >> 3) + 7) * 15 + ((i & 7) - (j & 7) + 7);
        relb[r] = btab[rel * 6 + h];
    }
}

// ---------------- k2: x -> pre-fragmented bf16 ----------------
// xbf element offset: b*12288 + ks*2048 + tt*512 + lane*8   (bf16 units)
__global__ __launch_bounds__(256) void prep_x(const float* __restrict__ xg_all,
                                              bf16* __restrict__ xbf)
{
    const int b = blockIdx.x;
    const float* xg = xg_all + (size_t)b * 11520;
    bf16* dst = xbf + (size_t)b * 12288;
    for (int e = threadIdx.x; e < 1536; e += 256) {
        const int lane = e & 63;
        const int tt = (e >> 6) & 3;
        const int ks = e >> 8;
        const int l15 = lane & 15, g = lane >> 4;
        const int row = 16 * tt + l15;
        const int c0 = 32 * ks + 8 * g;
        bf16x8 v;
        #pragma unroll
        for (int s = 0; s < 8; s++) {
            const int c = c0 + s;
            v[s] = (bf16)((c < 180) ? xg[row * 180 + c] : 0.f);
        }
        *reinterpret_cast<bf16x8*>(dst + (size_t)e * 8) = v;
    }
}

// ---------------- x-fragment loader (both paths) ----------------
template <int XBF>
__device__ __forceinline__ bf16x8 load_xfrag(const float* __restrict__ xg,
                                             const bf16* __restrict__ xw,
                                             int ks, int tt, int l15, int g, int lane)
{
    if (XBF) {
        return *reinterpret_cast<const bf16x8*>(xw + ks * 2048 + tt * 512 + lane * 8);
    } else {
        const int row = 16 * tt + l15;
        const int c0 = 32 * ks + 8 * g;
        bf16x8 v;
        if (c0 + 7 < 180) {
            const float4 a0 = *reinterpret_cast<const float4*>(xg + row * 180 + c0);
            const float4 a1 = *reinterpret_cast<const float4*>(xg + row * 180 + c0 + 4);
            v[0] = (bf16)a0.x; v[1] = (bf16)a0.y; v[2] = (bf16)a0.z; v[3] = (bf16)a0.w;
            v[4] = (bf16)a1.x; v[5] = (bf16)a1.y; v[6] = (bf16)a1.z; v[7] = (bf16)a1.w;
        } else {
            #pragma unroll
            for (int s = 0; s < 8; s++) {
                const int c = c0 + s;
                v[s] = (bf16)((c < 180) ? xg[row * 180 + c] : 0.f);
            }
        }
        return v;
    }
}

// ---------------- k3: attention, 2 waves/block, no LDS, no barriers ----------
template <int XBF>
__global__ __launch_bounds__(128, 4)
void swin_attn(const float* __restrict__ xg_all,
               const float* __restrict__ mask_all,
               const bf16* __restrict__ wqkvT,
               const float* __restrict__ relb,
               const bf16* __restrict__ xbf,
               float* __restrict__ outg)
{
    const int tid  = threadIdx.x;
    const int lane = tid & 63;
    const int l15  = lane & 15;
    const int g    = lane >> 4;
    const int bb   = blockIdx.x;
    const int b    = bb / 3;
    const int hp   = bb - 3 * b;
    const int h    = 2 * hp + (tid >> 6);          // this wave's head

    const float* xg    = xg_all + (size_t)b * 11520;
    const bf16*  xw    = xbf + (size_t)b * 12288;
    const float* maskw = mask_all + (size_t)(b & 1023) * 4096;
    const bf16*  wqh   = wqkvT + h * 18432;        // [6 ct][16][192]
    const int rowoff   = l15 * 192 + 8 * g;

    // ---- q-pass (swapped mfma: lane=token, regs=channels)
    bf16x8 qf[4];                                  // slot s <-> d = 16*(s>=4)+4g+(s&3)
    {
        f32x4 aq[2][4];
        #pragma unroll
        for (int ct = 0; ct < 2; ct++)
            #pragma unroll
            for (int tt = 0; tt < 4; tt++) aq[ct][tt] = (f32x4)0.f;
        for (int ks = 0; ks < 6; ks++) {
            bf16x8 xf[4];
            #pragma unroll
            for (int tt = 0; tt < 4; tt++) xf[tt] = load_xfrag<XBF>(xg, xw, ks, tt, l15, g, lane);
            #pragma unroll
            for (int ct = 0; ct < 2; ct++) {
                const bf16x8 wf = *reinterpret_cast<const bf16x8*>(wqh + ct * 3072 + rowoff + 32 * ks);
                #pragma unroll
                for (int tt = 0; tt < 4; tt++) aq[ct][tt] = MFMA(wf, xf[tt], aq[ct][tt]);
            }
        }
        #pragma unroll
        for (int tt = 0; tt < 4; tt++)
            #pragma unroll
            for (int s = 0; s < 8; s++)
                qf[tt][s] = (bf16)(aq[s >> 2][tt][s & 3] * 0.18257418583505537f);
    }
    __builtin_amdgcn_sched_barrier(0);

    // ---- k-pass
    bf16x8 kf[4];
    {
        f32x4 ak[2][4];
        #pragma unroll
        for (int ct = 0; ct < 2; ct++)
            #pragma unroll
            for (int tt = 0; tt < 4; tt++) ak[ct][tt] = (f32x4)0.f;
        for (int ks = 0; ks < 6; ks++) {
            bf16x8 xf[4];
            #pragma unroll
            for (int tt = 0; tt < 4; tt++) xf[tt] = load_xfrag<XBF>(xg, xw, ks, tt, l15, g, lane);
            #pragma unroll
            for (int ct = 0; ct < 2; ct++) {
                const bf16x8 wf = *reinterpret_cast<const bf16x8*>(wqh + (2 + ct) * 3072 + rowoff + 32 * ks);
                #pragma unroll
                for (int tt = 0; tt < 4; tt++) ak[ct][tt] = MFMA(wf, xf[tt], ak[ct][tt]);
            }
        }
        #pragma unroll
        for (int tt = 0; tt < 4; tt++)
            #pragma unroll
            for (int s = 0; s < 8; s++)
                kf[tt][s] = (bf16)(ak[s >> 2][tt][s & 3]);
    }
    __builtin_amdgcn_sched_barrier(0);

    // ---- QK^T + softmax (it-sequential)
    bf16x8 pf[4][2];                               // [it][k2]
    {
        const float* relh = relb + h * 4096;
        #pragma unroll
        for (int it = 0; it < 4; it++) {
            f32x4 stj[4];                          // j = 16jt+4g+r, i = 16it+l15
            #pragma unroll
            for (int jt = 0; jt < 4; jt++) stj[jt] = MFMA(kf[jt], qf[it], (f32x4)0.f);

            const int i = 16 * it + l15;
            const float* rbb = relh + i * 64 + 4 * g;
            const float* mkb = maskw + i * 64 + 4 * g;
            float mx = -1e30f;
            #pragma unroll
            for (int jt = 0; jt < 4; jt++) {
                const float4 rb = *reinterpret_cast<const float4*>(rbb + 16 * jt);
                const float4 mk = *reinterpret_cast<const float4*>(mkb + 16 * jt);
                stj[jt][0] += rb.x + mk.x;
                stj[jt][1] += rb.y + mk.y;
                stj[jt][2] += rb.z + mk.z;
                stj[jt][3] += rb.w + mk.w;
                #pragma unroll
                for (int r = 0; r < 4; r++) mx = fmaxf(mx, stj[jt][r]);
            }
            mx = fmaxf(mx, __shfl_xor(mx, 16));
            mx = fmaxf(mx, __shfl_xor(mx, 32));
            float sum = 0.f;
            #pragma unroll
            for (int jt = 0; jt < 4; jt++)
                #pragma unroll
                for (int r = 0; r < 4; r++) {
                    const float e = __expf(stj[jt][r] - mx);
                    stj[jt][r] = e;
                    sum += e;
                }
            sum += __shfl_xor(sum, 16);
            sum += __shfl_xor(sum, 32);
            const float inv = 1.0f / sum;
            #pragma unroll
            for (int k2 = 0; k2 < 2; k2++)
                #pragma unroll
                for (int s = 0; s < 8; s++)
                    pf[it][k2][s] = (bf16)(stj[2 * k2 + (s >> 2)][s & 3] * inv);
        }
    }
    __builtin_amdgcn_sched_barrier(0);

    // ---- v-pass (normal mfma: lane=channel, regs=tokens)
    bf16x8 vf[2][2];                               // [cv][k2]
    {
        f32x4 av[4][2];
        #pragma unroll
        for (int tt = 0; tt < 4; tt++) { av[tt][0] = (f32x4)0.f; av[tt][1] = (f32x4)0.f; }
        for (int ks = 0; ks < 6; ks++) {
            bf16x8 xf[4];
            #pragma unroll
            for (int tt = 0; tt < 4; tt++) xf[tt] = load_xfrag<XBF>(xg, xw, ks, tt, l15, g, lane);
            #pragma unroll
            for (int cv = 0; cv < 2; cv++) {
                const bf16x8 wf = *reinterpret_cast<const bf16x8*>(wqh + (4 + cv) * 3072 + rowoff + 32 * ks);
                #pragma unroll
                for (int tt = 0; tt < 4; tt++) av[tt][cv] = MFMA(xf[tt], wf, av[tt][cv]);
            }
        }
        #pragma unroll
        for (int cv = 0; cv < 2; cv++)
            #pragma unroll
            for (int k2 = 0; k2 < 2; k2++)
                #pragma unroll
                for (int s = 0; s < 8; s++)
                    vf[cv][k2][s] = (bf16)(av[2 * k2 + (s >> 2)][cv][s & 3]);
    }
    __builtin_amdgcn_sched_barrier(0);

    // ---- PV, all in registers
    f32x4 zacc[4][2];                              // [it][cv]: z[16it+4g+r][16cv+l15]
    #pragma unroll
    for (int it = 0; it < 4; it++) { zacc[it][0] = (f32x4)0.f; zacc[it][1] = (f32x4)0.f; }
    #pragma unroll
    for (int k2 = 0; k2 < 2; k2++)
        #pragma unroll
        for (int cv = 0; cv < 2; cv++)
            #pragma unroll
            for (int it = 0; it < 4; it++)
                zacc[it][cv] = MFMA(pf[it][k2], vf[cv][k2], zacc[it][cv]);

    // ---- z -> d_out window region as bf16 [64][192] (k-contiguous for proj)
    bf16* zb = (bf16*)(outg + (size_t)b * 11520);
    #pragma unroll
    for (int cv = 0; cv < 2; cv++) {
        const int d = 16 * cv + l15;
        if (d < 30) {
            #pragma unroll
            for (int it = 0; it < 4; it++)
                #pragma unroll
                for (int r = 0; r < 4; r++)
                    zb[(16 * it + 4 * g + r) * 192 + h * 30 + d] = (bf16)zacc[it][cv][r];
        }
    }
}

// ---------------- k4: proj GEMM (reads z from out region, overwrites) --------
__global__ __launch_bounds__(256, 4)
void proj_kernel(const bf16* __restrict__ wprojT,
                 const float* __restrict__ bproj,
                 float* __restrict__ outg)
{
    __shared__ __align__(16) short zs[64 * 200];
    const int b    = blockIdx.x;
    const int tid  = threadIdx.x;
    const int w2   = tid >> 6;
    const int lane = tid & 63;
    const int l15  = lane & 15;
    const int g    = lane >> 4;

    const bf16* zsrc = (const bf16*)(outg + (size_t)b * 11520);
    // Race-free staging: each (row, col-slot) written by exactly one thread.
    // Cols 0..175 from z, 176..179 from z, 180..199 zeroed (z cols 180..191
    // in d_out are stale garbage on graph replays -- never read them as data).
    for (int e = tid; e < 1600; e += 256) {        // 64 rows x 25 slots
        const int row = e / 25;
        const int sl  = e - row * 25;
        short* const zrow = zs + row * 200;
        if (sl < 22) {
            *reinterpret_cast<uint4*>(zrow + sl * 8) =
                *reinterpret_cast<const uint4*>(zsrc + row * 192 + sl * 8);
        } else if (sl == 22) {
            *reinterpret_cast<uint2*>(zrow + 176) =
                *reinterpret_cast<const uint2*>(zsrc + row * 192 + 176);
            *reinterpret_cast<uint2*>(zrow + 180) = make_uint2(0u, 0u);
        } else if (sl == 23) {
            *reinterpret_cast<uint4*>(zrow + 184) = make_uint4(0u, 0u, 0u, 0u);
        } else {
            *reinterpret_cast<uint4*>(zrow + 192) = make_uint4(0u, 0u, 0u, 0u);
        }
    }
    __syncthreads();

    f32x4 pa[4][3];
    #pragma unroll
    for (int mt = 0; mt < 4; mt++)
        #pragma unroll
        for (int q3 = 0; q3 < 3; q3++) pa[mt][q3] = (f32x4)0.f;

    for (int ks = 0; ks < 6; ks++) {
        bf16x8 zf[4];
        #pragma unroll
        for (int mt = 0; mt < 4; mt++)
            zf[mt] = *reinterpret_cast<const bf16x8*>(zs + (16 * mt + l15) * 200 + 32 * ks + 8 * g);
        #pragma unroll
        for (int q3 = 0; q3 < 3; q3++) {
            const int nt = 3 * w2 + q3;
            const bf16x8 wf = *reinterpret_cast<const bf16x8*>(
                wprojT + (nt * 16 + l15) * 192 + 32 * ks + 8 * g);
            #pragma unroll
            for (int mt = 0; mt < 4; mt++)
                pa[mt][q3] = MFMA(zf[mt], wf, pa[mt][q3]);
        }
    }
    #pragma unroll
    for (int q3 = 0; q3 < 3; q3++) {
        const int n = (3 * w2 + q3) * 16 + l15;
        if (n < 180) {
            const float bn = bproj[n];
            float* const ob = outg + (size_t)b * 11520 + n;
            #pragma unroll
            for (int mt = 0; mt < 4; mt++)
                #pragma unroll
                for (int r = 0; r < 4; r++)
                    ob[(16 * mt + 4 * g + r) * 180] = pa[mt][q3][r] + bn;
        }
    }
}

extern "C" void kernel_launch(void* const* d_in, const int* in_sizes, int n_in,
                              void* d_out, int out_size, void* d_ws, size_t ws_size,
                              hipStream_t stream) {
    const float* windows = (const float*)d_in[0];
    const float* mask    = (const float*)d_in[1];
    const float* wqkv    = (const float*)d_in[2];
    const float* btab    = (const float*)d_in[3];
    const float* wproj   = (const float*)d_in[4];
    const float* bproj   = (const float*)d_in[5];

    bf16*  wqkvT  = (bf16*)d_ws;                          // 221184 B
    bf16*  wprojT = (bf16*)((char*)d_ws + 221184);        //  73728 B
    float* relb   = (float*)((char*)d_ws + 294912);       //  98304 B
    bf16*  xbf    = (bf16*)((char*)d_ws + 393216);        // 100663296 B (optional)

    const bool use_xbf = ws_size >= (size_t)393216 + (size_t)4096 * 12288 * 2;

    hipLaunchKernelGGL(prep_w, dim3(672), dim3(256), 0, stream,
                       wqkv, wproj, btab, wqkvT, wprojT, relb);
    if (use_xbf) {
        hipLaunchKernelGGL(prep_x, dim3(4096), dim3(256), 0, stream, windows, xbf);
        hipLaunchKernelGGL(swin_attn<1>, dim3(12288), dim3(128), 0, stream,
                           windows, mask, wqkvT, relb, xbf, (float*)d_out);
    } else {
        hipLaunchKernelGGL(swin_attn<0>, dim3(12288), dim3(128), 0, stream,
                           windows, mask, wqkvT, relb, xbf, (float*)d_out);
    }
    hipLaunchKernelGGL(proj_kernel, dim3(4096), dim3(256), 0, stream,
                       wprojT, bproj, (float*)d_out);
}

// Round 9
// 290.602 us; speedup vs baseline: 1.8762x; 1.8762x over previous
//
#include <hip/hip_runtime.h>

// Swin window attention, fused register-resident MFMA pipeline. 1 block
// (6 waves) per window; wave w owns head w. B=4096, N=64, C=180, H=6, D=30.
//
// Round-9 = round-5 (341 us, best) + exposed-HBM-latency fixes:
//   - phase 1: batch all 15 x-loads into regs, single wait, then cvt+LDS
//   - softmax: mask+relb prefetched one `it` ahead (it=0 before QK^T loop)
//   - qk-pass re-merged at (384,4) WITH fences (r4 spilled w/o fences,
//     r6 spilled at the 102-reg cap; ~100 regs fits 128)
//   - #pragma unroll on all ks loops
//
// d_ws (prep_w fills every launch):
//   [0)       wqkvT  bf16 [576][192]  oc = h*96 + sec*32 + d  (0=q,1=k,2=v)
//   [221184)  wprojT bf16 [192][192]  n-major
//   [294912)  relb   f32  [6][64][64] pre-gathered rel-pos bias
//
// LDS: one [64][200] short buffer (x bf16, later z bf16). 25.6 KB.
//
// Fragment-permutation trick (verified r2-r5): MFMA contracts A-slot(g,s) with
// B-slot(g,s); q/k fragments carry d(g,s)=16*(s>=4)+4g+(s&3) and P/V fragments
// carry j(g,s,k2)=32k2+16*(s>=4)+4g+(s&3) -- identical bijections on both
// operands, so no cross-lane traffic anywhere.

typedef __bf16 bf16;
typedef bf16 bf16x8 __attribute__((ext_vector_type(8)));
typedef float f32x4 __attribute__((ext_vector_type(4)));

#define MFMA(a, b, c) __builtin_amdgcn_mfma_f32_16x16x32_bf16(a, b, c, 0, 0, 0)

__global__ void prep_w(const float* __restrict__ wqkv,
                       const float* __restrict__ wproj,
                       const float* __restrict__ btab,
                       bf16* __restrict__ wqkvT,
                       bf16* __restrict__ wprojT,
                       float* __restrict__ relb)
{
    const int idx = blockIdx.x * 256 + threadIdx.x;
    if (idx < 110592) {                          // wqkvT [576][192]
        const int oc = idx / 192, kk = idx - oc * 192;
        const int h = oc / 96, r = oc - h * 96;
        const int sec = r >> 5, d = r & 31;
        wqkvT[idx] = (bf16)((kk < 180 && d < 30) ? wqkv[kk * 540 + sec * 180 + h * 30 + d] : 0.f);
    } else if (idx < 147456) {                   // wprojT [192][192]
        const int r = idx - 110592;
        const int n = r / 192, k = r - n * 192;
        wprojT[r] = (bf16)((n < 180 && k < 180) ? wproj[k * 180 + n] : 0.f);
    } else if (idx < 172032) {                   // relb [6][64][64]
        const int r = idx - 147456;
        const int h = r >> 12;
        const int ij = r & 4095;
        const int i = ij >> 6, j = ij & 63;
        const int rel = ((i >> 3) - (j >> 3) + 7) * 15 + ((i & 7) - (j & 7) + 7);
        relb[r] = btab[rel * 6 + h];
    }
}

__global__ __launch_bounds__(384, 4)
void swin_mfma(const float* __restrict__ xg_all,
               const float* __restrict__ mask_all,
               const float* __restrict__ bproj,
               const bf16* __restrict__ wqkvT,
               const bf16* __restrict__ wprojT,
               const float* __restrict__ relb,
               float* __restrict__ outg)
{
    __shared__ __align__(16) short xb[64 * 200];   // x bf16, later z bf16

    const int b    = blockIdx.x;
    const int tid  = threadIdx.x;
    const int w    = tid >> 6;                     // wave = head, 0..5
    const int lane = tid & 63;
    const int l15  = lane & 15;
    const int g    = lane >> 4;                    // 0..3

    const float* xg    = xg_all + (size_t)b * 11520;
    const float* maskw = mask_all + (size_t)(b & 1023) * 4096;

    // ---- phase 1: x -> bf16 xb. Batch ALL 15 loads first (one latency hit),
    // then convert+store. 5760 float2 = 384 thr x 15 exactly.
    {
        float2 xv[15];
        #pragma unroll
        for (int u = 0; u < 15; u++)
            xv[u] = *reinterpret_cast<const float2*>(xg + 2 * (tid + 384 * u));
        for (int e = tid; e < 640; e += 384) {     // zero pad cols [180..200)
            const int i = e / 10;
            ((unsigned*)(xb + i * 200 + 180))[e - i * 10] = 0u;
        }
        #pragma unroll
        for (int u = 0; u < 15; u++) {
            const int e = tid + 384 * u;
            const int i = e / 90;
            const int c = 2 * e - i * 180;
            const unsigned lo = (unsigned)__builtin_bit_cast(unsigned short, (bf16)xv[u].x);
            const unsigned hi = (unsigned)__builtin_bit_cast(unsigned short, (bf16)xv[u].y);
            *reinterpret_cast<unsigned*>(xb + i * 200 + c) = lo | (hi << 16);
        }
    }
    __syncthreads();

    const bf16* wqh = wqkvT + (size_t)(w * 96) * 192;
    const int rowoff = l15 * 192 + 8 * g;

    // ---- phase 2qk: q,k for head w (swapped mfma: lane=token, regs=channels)
    bf16x8 qf[4], kf[4];                           // slot s <-> d = 16*(s>=4)+4g+(s&3)
    {
        f32x4 aqk[4][4];                           // [ct][tt] ct: q0,q1,k0,k1
        #pragma unroll
        for (int ct = 0; ct < 4; ct++)
            #pragma unroll
            for (int tt = 0; tt < 4; tt++) aqk[ct][tt] = (f32x4)0.f;
        #pragma unroll
        for (int ks = 0; ks < 6; ks++) {
            bf16x8 xf[4];
            #pragma unroll
            for (int tt = 0; tt < 4; tt++)
                xf[tt] = *reinterpret_cast<const bf16x8*>(xb + (16 * tt + l15) * 200 + 32 * ks + 8 * g);
            #pragma unroll
            for (int ct = 0; ct < 4; ct++) {
                const bf16x8 wf = *reinterpret_cast<const bf16x8*>(wqh + ct * 3072 + rowoff + 32 * ks);
                #pragma unroll
                for (int tt = 0; tt < 4; tt++)
                    aqk[ct][tt] = MFMA(wf, xf[tt], aqk[ct][tt]);
            }
        }
        #pragma unroll
        for (int tt = 0; tt < 4; tt++)
            #pragma unroll
            for (int s = 0; s < 8; s++) {
                qf[tt][s] = (bf16)(aqk[s >> 2][tt][s & 3] * 0.18257418583505537f);
                kf[tt][s] = (bf16)(aqk[2 + (s >> 2)][tt][s & 3]);
            }
    }
    __builtin_amdgcn_sched_barrier(0);

    // ---- phase 3: QK^T + softmax, it-sequential, bias prefetched 1 it ahead
    bf16x8 pf[4][2];                               // [it][k2]
    {
        const float* relh = relb + w * 4096;
        float4 rbc[4], mkc[4];                     // current-it bias (prefetched)
        {
            const float* rbb = relh + l15 * 64 + 4 * g;
            const float* mkb = maskw + l15 * 64 + 4 * g;
            #pragma unroll
            for (int jt = 0; jt < 4; jt++) {
                rbc[jt] = *reinterpret_cast<const float4*>(rbb + 16 * jt);
                mkc[jt] = *reinterpret_cast<const float4*>(mkb + 16 * jt);
            }
        }
        #pragma unroll
        for (int it = 0; it < 4; it++) {
            f32x4 stj[4];                          // j = 16jt+4g+r, i = 16it+l15
            #pragma unroll
            for (int jt = 0; jt < 4; jt++) stj[jt] = MFMA(kf[jt], qf[it], (f32x4)0.f);

            float4 rbn[4], mkn[4];                 // prefetch next it's bias
            if (it < 3) {
                const int i1 = 16 * (it + 1) + l15;
                const float* rbb = relh + i1 * 64 + 4 * g;
                const float* mkb = maskw + i1 * 64 + 4 * g;
                #pragma unroll
                for (int jt = 0; jt < 4; jt++) {
                    rbn[jt] = *reinterpret_cast<const float4*>(rbb + 16 * jt);
                    mkn[jt] = *reinterpret_cast<const float4*>(mkb + 16 * jt);
                }
            }

            float mx = -1e30f;
            #pragma unroll
            for (int jt = 0; jt < 4; jt++) {
                stj[jt][0] += rbc[jt].x + mkc[jt].x;
                stj[jt][1] += rbc[jt].y + mkc[jt].y;
                stj[jt][2] += rbc[jt].z + mkc[jt].z;
                stj[jt][3] += rbc[jt].w + mkc[jt].w;
                #pragma unroll
                for (int r = 0; r < 4; r++) mx = fmaxf(mx, stj[jt][r]);
            }
            mx = fmaxf(mx, __shfl_xor(mx, 16));
            mx = fmaxf(mx, __shfl_xor(mx, 32));
            float sum = 0.f;
            #pragma unroll
            for (int jt = 0; jt < 4; jt++)
                #pragma unroll
                for (int r = 0; r < 4; r++) {
                    const float e = __expf(stj[jt][r] - mx);
                    stj[jt][r] = e;
                    sum += e;
                }
            sum += __shfl_xor(sum, 16);
            sum += __shfl_xor(sum, 32);
            const float inv = 1.0f / sum;
            #pragma unroll
            for (int k2 = 0; k2 < 2; k2++)
                #pragma unroll
                for (int s = 0; s < 8; s++)
                    pf[it][k2][s] = (bf16)(stj[2 * k2 + (s >> 2)][s & 3] * inv);

            if (it < 3) {
                #pragma unroll
                for (int jt = 0; jt < 4; jt++) { rbc[jt] = rbn[jt]; mkc[jt] = mkn[jt]; }
            }
        }
    }
    __builtin_amdgcn_sched_barrier(0);

    // ---- phase 2v (deferred): v (normal mfma: lane=channel, regs=tokens)
    bf16x8 vf[2][2];                               // [cv][k2]
    {
        f32x4 av[4][2];                            // [tt][cv]
        #pragma unroll
        for (int tt = 0; tt < 4; tt++) { av[tt][0] = (f32x4)0.f; av[tt][1] = (f32x4)0.f; }
        #pragma unroll
        for (int ks = 0; ks < 6; ks++) {
            bf16x8 xf[4];
            #pragma unroll
            for (int tt = 0; tt < 4; tt++)
                xf[tt] = *reinterpret_cast<const bf16x8*>(xb + (16 * tt + l15) * 200 + 32 * ks + 8 * g);
            #pragma unroll
            for (int cv = 0; cv < 2; cv++) {
                const bf16x8 wf = *reinterpret_cast<const bf16x8*>(wqh + (4 + cv) * 3072 + rowoff + 32 * ks);
                #pragma unroll
                for (int tt = 0; tt < 4; tt++)
                    av[tt][cv] = MFMA(xf[tt], wf, av[tt][cv]);
            }
        }
        #pragma unroll
        for (int cv = 0; cv < 2; cv++)
            #pragma unroll
            for (int k2 = 0; k2 < 2; k2++)
                #pragma unroll
                for (int s = 0; s < 8; s++)
                    vf[cv][k2][s] = (bf16)(av[2 * k2 + (s >> 2)][cv][s & 3]);
    }
    __builtin_amdgcn_sched_barrier(0);

    // ---- phase 4: PV, all in registers
    f32x4 zacc[4][2];                              // [it][cv]: z[16it+4g+r][16cv+l15]
    #pragma unroll
    for (int it = 0; it < 4; it++) { zacc[it][0] = (f32x4)0.f; zacc[it][1] = (f32x4)0.f; }
    #pragma unroll
    for (int k2 = 0; k2 < 2; k2++)
        #pragma unroll
        for (int cv = 0; cv < 2; cv++)
            #pragma unroll
            for (int it = 0; it < 4; it++)
                zacc[it][cv] = MFMA(pf[it][k2], vf[cv][k2], zacc[it][cv]);

    __syncthreads();                               // all waves done reading xb
    // z -> zb (aliases xb; pad cols [180..200) still zero from phase 1)
    #pragma unroll
    for (int cv = 0; cv < 2; cv++) {
        const int d = 16 * cv + l15;
        if (d < 30) {
            #pragma unroll
            for (int it = 0; it < 4; it++)
                #pragma unroll
                for (int r = 0; r < 4; r++)
                    xb[(16 * it + 4 * g + r) * 200 + w * 30 + d] =
                        __builtin_bit_cast(short, (bf16)zacc[it][cv][r]);
        }
    }
    __syncthreads();

    // ---- phase 5: proj GEMM + bias -> out
    f32x4 pa[4][2];
    #pragma unroll
    for (int mt = 0; mt < 4; mt++) { pa[mt][0] = (f32x4)0.f; pa[mt][1] = (f32x4)0.f; }
    #pragma unroll
    for (int ks = 0; ks < 6; ks++) {
        bf16x8 zf[4];
        #pragma unroll
        for (int mt = 0; mt < 4; mt++)
            zf[mt] = *reinterpret_cast<const bf16x8*>(xb + (16 * mt + l15) * 200 + 32 * ks + 8 * g);
        #pragma unroll
        for (int q2 = 0; q2 < 2; q2++) {
            const bf16x8 wf = *reinterpret_cast<const bf16x8*>(
                wprojT + ((2 * w + q2) * 16 + l15) * 192 + 32 * ks + 8 * g);
            #pragma unroll
            for (int mt = 0; mt < 4; mt++)
                pa[mt][q2] = MFMA(zf[mt], wf, pa[mt][q2]);
        }
    }
    #pragma unroll
    for (int q2 = 0; q2 < 2; q2++) {
        const int n = (2 * w + q2) * 16 + l15;
        if (n < 180) {
            const float bn = bproj[n];
            float* const ob = outg + (size_t)b * 11520 + n;
            #pragma unroll
            for (int mt = 0; mt < 4; mt++)
                #pragma unroll
                for (int r = 0; r < 4; r++)
                    ob[(16 * mt + 4 * g + r) * 180] = pa[mt][q2][r] + bn;
        }
    }
}

extern "C" void kernel_launch(void* const* d_in, const int* in_sizes, int n_in,
                              void* d_out, int out_size, void* d_ws, size_t ws_size,
                              hipStream_t stream) {
    const float* windows = (const float*)d_in[0];
    const float* mask    = (const float*)d_in[1];
    const float* wqkv    = (const float*)d_in[2];
    const float* btab    = (const float*)d_in[3];
    const float* wproj   = (const float*)d_in[4];
    const float* bproj   = (const float*)d_in[5];

    bf16*  wqkvT  = (bf16*)d_ws;
    bf16*  wprojT = (bf16*)((char*)d_ws + 221184);
    float* relb   = (float*)((char*)d_ws + 294912);

    hipLaunchKernelGGL(prep_w, dim3(672), dim3(256), 0, stream,
                       wqkv, wproj, btab, wqkvT, wprojT, relb);
    hipLaunchKernelGGL(swin_mfma, dim3(4096), dim3(384), 0, stream,
                       windows, mask, bproj, wqkvT, wprojT, relb, (float*)d_out);
}